// Round 1
// baseline (2521.177 us; speedup 1.0000x reference)
//
#include <hip/hip_runtime.h>
#include <hip/hip_bf16.h>

// HMM backward recursion, B=32, T=256, H=1024, V=50257.
// y_s[b,i] = N_{s-1}[b] + log( sum_j expA[i,j] * Y_{s-1}[b,j] ) + e_t[b,i]
// with Y_s = exp(y_s - N_s), N_s = max_i y_{s-1}[b,i]  (valid upper bound, y monotone-decreasing)

#define Hdim 1024
#define Bdim 32
#define Tdim 256
#define Vdim 50257
#define NWG  16
#define SLICE 64                 // Hdim / NWG rows of A per workgroup

typedef __attribute__((ext_vector_type(8))) __bf16 bf16x8;
typedef __attribute__((ext_vector_type(4))) float  f32x4;

// workspace layout (bytes)
#define OFF_ABF   0                         // exp(alpha) bf16: 1024*1024*2 = 2097152
#define OFF_YBUF  2097152                   // 2 * 32*1024 bf16 = 131072
#define OFF_LBUF  (OFF_YBUF + 131072)       // 2 * NWG*32 f32  = 4096
#define OFF_PSUM  (OFF_LBUF + 4096)         // 32 f32 (pad 128)
#define OFF_RBUF  (OFF_PSUM + 128)          // 32 f32 (pad 128)
#define OFF_CNT   (OFF_RBUF + 128)          // u32 (pad 128)
#define OFF_FLAG  (OFF_CNT + 128)           // u32 (pad 128)
#define WS_NEED   (OFF_FLAG + 128)

// LDS carve (dynamic): A slice (swizzled) + small scratch
#define SM_A      131072                    // 64 rows x 1024 bf16
#define SM_LTMP   (SM_A)                    // 512 f32  = 2048
#define SM_GSH    (SM_LTMP + 2048)          // 32 f32
#define SM_LTILE  (SM_GSH + 128)            // 4*32 f32 = 512
#define SM_XSH    (SM_LTILE + 512)          // 32 i32
#define SMEM_BYTES (SM_XSH + 128)

__global__ void k_expA(const float* __restrict__ alpha, __bf16* __restrict__ Abf) {
    int idx = (blockIdx.x * 256 + threadIdx.x) * 4;
    float4 v = *(const float4*)(alpha + idx);
    union { __bf16 h[4]; uint2 u; } cv;
    cv.h[0] = (__bf16)__expf(v.x);
    cv.h[1] = (__bf16)__expf(v.y);
    cv.h[2] = (__bf16)__expf(v.z);
    cv.h[3] = (__bf16)__expf(v.w);
    *(uint2*)(Abf + idx) = cv.u;
}

__device__ __forceinline__ void gbar(unsigned* cnt, unsigned* flag, unsigned phase) {
    __syncthreads();   // compiler drains vmcnt here: all our global stores complete
    if (threadIdx.x == 0) {
        unsigned want = phase + 1u;
        unsigned prev = __hip_atomic_fetch_add(cnt, 1u, __ATOMIC_ACQ_REL, __HIP_MEMORY_SCOPE_AGENT);
        if (prev == want * (unsigned)NWG - 1u) {
            __hip_atomic_store(flag, want, __ATOMIC_RELEASE, __HIP_MEMORY_SCOPE_AGENT);
        } else {
            while (__hip_atomic_load(flag, __ATOMIC_RELAXED, __HIP_MEMORY_SCOPE_AGENT) < want)
                __builtin_amdgcn_s_sleep(2);
            (void)__hip_atomic_load(flag, __ATOMIC_ACQUIRE, __HIP_MEMORY_SCOPE_AGENT);
        }
    }
    __syncthreads();
}

// write Y = exp(y - Gc) slice, publish per-WG per-b max of y into Lbw
__device__ __forceinline__ void store_phase(const float y[2][4], const float Gc[4],
                                            __bf16* Ybw, float* Lbw, float* Ltile,
                                            int w, int li, int b0, int i0, int p) {
    #pragma unroll
    for (int r = 0; r < 4; ++r) {
        #pragma unroll
        for (int u = 0; u < 2; ++u) {
            float Yn = __expf(y[u][r] - Gc[r]);
            Ybw[(b0 + r) * Hdim + i0 + u * 16] = (__bf16)Yn;
        }
        float m = fmaxf(y[0][r], y[1][r]);
        m = fmaxf(m, __shfl_xor(m, 1, 16));
        m = fmaxf(m, __shfl_xor(m, 2, 16));
        m = fmaxf(m, __shfl_xor(m, 4, 16));
        m = fmaxf(m, __shfl_xor(m, 8, 16));
        if (li == 0) Ltile[w * 32 + b0 + r] = m;
    }
    __syncthreads();
    if (threadIdx.x < 32) {
        int b = threadIdx.x;
        int mbb = b >> 4;
        float L = fmaxf(Ltile[mbb * 32 + b], Ltile[(mbb + 2) * 32 + b]);
        Lbw[p * 32 + b] = L;
    }
}

__launch_bounds__(256, 1)
__global__ void k_hmm(const int* __restrict__ x,
                      const float* __restrict__ beta,
                      const float* __restrict__ gamma,
                      const __bf16* __restrict__ Abf,
                      __bf16* __restrict__ Ybuf,    // [2][32][1024]
                      float* __restrict__ Lbuf,     // [2][NWG][32]
                      float* __restrict__ Psum,     // [32]
                      float* __restrict__ Rbuf,     // [32]
                      unsigned* cnt, unsigned* flag)
{
    extern __shared__ char smem[];
    char*  Asl   = smem;
    float* Ltmp  = (float*)(smem + SM_LTMP);
    float* Gsh   = (float*)(smem + SM_GSH);
    float* Ltile = (float*)(smem + SM_LTILE);
    int*   xsh   = (int*)(smem + SM_XSH);

    const int p   = blockIdx.x;
    const int tid = threadIdx.x;
    const int w   = tid >> 6;      // wave 0..3
    const int l   = tid & 63;
    const int g   = l >> 4;        // k-group / D-row-group
    const int li  = l & 15;
    const int mb  = w & 1;         // batch 16-block
    const int np  = w >> 1;        // n-block pair
    const int b0  = mb * 16 + g * 4;               // batch base (+r)
    const int i0  = p * SLICE + np * 32 + li;      // global i for u=0 (+16 for u=1)

    // ---- stage A slice rows [p*64, p*64+64) into LDS, XOR-swizzled for b128 reads ----
    #pragma unroll
    for (int rep = 0; rep < 32; ++rep) {
        int flat = rep * 256 + tid;          // 0..8191 16B-chunks
        int row  = flat >> 7;                // 0..63
        int c16  = flat & 127;
        uint4 v = *(const uint4*)((const char*)Abf + (size_t)(p * 64 + row) * 2048 + c16 * 16);
        int off = (row * 2048 + c16 * 16) ^ ((row & 7) << 4);
        *(uint4*)(Asl + off) = v;
    }

    // ---- init: y0 = e[:, T-1]; Y0 = exp(y0 - 0) ----
    if (tid < 32) xsh[tid] = x[tid * Tdim + (Tdim - 1)];
    __syncthreads();
    {
        float y0[2][4];
        #pragma unroll
        for (int u = 0; u < 2; ++u)
            #pragma unroll
            for (int r = 0; r < 4; ++r)
                y0[u][r] = beta[(size_t)(i0 + u * 16) * Vdim + xsh[b0 + r]];
        float Gc0[4] = {0.f, 0.f, 0.f, 0.f};
        store_phase(y0, Gc0, Ybuf, Lbuf, Ltile, w, li, b0, i0, p);
    }
    gbar(cnt, flag, 0);

    float Nprev[4] = {0.f, 0.f, 0.f, 0.f};

    for (int s = 1; s < Tdim; ++s) {
        const int t = Tdim - 1 - s;
        const __bf16* Ybr = Ybuf + ((s - 1) & 1) * (Bdim * Hdim);
        __bf16*       Ybw = Ybuf + (s & 1)       * (Bdim * Hdim);
        const float*  Lbr = Lbuf + ((s - 1) & 1) * (NWG * 32);
        float*        Lbw = Lbuf + (s & 1)       * (NWG * 32);

        if (tid < 32)  xsh[tid] = x[tid * Tdim + t];
        if (tid < 128) *(float4*)(Ltmp + tid * 4) = *(const float4*)(Lbr + tid * 4);
        __syncthreads();

        // e prefetch (beta column gather, latency hidden under step)
        float ereg[2][4];
        #pragma unroll
        for (int u = 0; u < 2; ++u)
            #pragma unroll
            for (int r = 0; r < 4; ++r)
                ereg[u][r] = beta[(size_t)(i0 + u * 16) * Vdim + xsh[b0 + r]];

        float gl[2] = {0.f, 0.f};
        if (s == Tdim - 1) { gl[0] = gamma[i0]; gl[1] = gamma[i0 + 16]; }

        // global max per b from published per-WG maxes (same value in every WG)
        if (tid < 32) {
            float gm = Ltmp[tid];
            #pragma unroll
            for (int q = 1; q < NWG; ++q) gm = fmaxf(gm, Ltmp[q * 32 + tid]);
            Gsh[tid] = gm;
        }

        // Y fragment loads straight into registers (16 rows x 64B per wave-chunk)
        uint4 yreg[32];
        {
            const char* yrow = (const char*)Ybr + (size_t)(mb * 16 + li) * 2048 + g * 16;
            #pragma unroll
            for (int kc = 0; kc < 32; ++kc)
                yreg[kc] = *(const uint4*)(yrow + kc * 64);
        }
        __syncthreads();

        float Gcur[4];
        #pragma unroll
        for (int r = 0; r < 4; ++r) Gcur[r] = Gsh[b0 + r];

        // ---- K loop: S[b, i-slice] = sum_j expA[i,j] * Y[b,j] ----
        f32x4 acc0 = {0.f, 0.f, 0.f, 0.f}, acc1 = {0.f, 0.f, 0.f, 0.f};
        {
            const int ia = np * 32 + li;
            const int ib = ia + 16;
            const int basea = ia * 2048 + g * 16, xa = (ia & 7) << 4;
            const int baseb = ib * 2048 + g * 16, xb = (ib & 7) << 4;
            #pragma unroll
            for (int kc = 0; kc < 32; ++kc) {
                bf16x8 af0 = *(const bf16x8*)(Asl + ((basea + kc * 64) ^ xa));
                bf16x8 af1 = *(const bf16x8*)(Asl + ((baseb + kc * 64) ^ xb));
                bf16x8 yf  = __builtin_bit_cast(bf16x8, yreg[kc]);
                acc0 = __builtin_amdgcn_mfma_f32_16x16x32_bf16(yf, af0, acc0, 0, 0, 0);
                acc1 = __builtin_amdgcn_mfma_f32_16x16x32_bf16(yf, af1, acc1, 0, 0, 0);
            }
        }

        // ---- epilogue: y_s = N_{s-1} + log S + e_t ----
        float yv[2][4];
        #pragma unroll
        for (int r = 0; r < 4; ++r) {
            yv[0][r] = Nprev[r] + __logf(acc0[r]) + ereg[0][r];
            yv[1][r] = Nprev[r] + __logf(acc1[r]) + ereg[1][r];
        }

        if (s < Tdim - 1) {
            store_phase(yv, Gcur, Ybw, Lbw, Ltile, w, li, b0, i0, p);
            #pragma unroll
            for (int r = 0; r < 4; ++r) Nprev[r] = Gcur[r];
            gbar(cnt, flag, (unsigned)s);
        } else {
            // final: out[b] = logsumexp_i(gamma[i] + y[b,i]) ; partials via atomicAdd
            #pragma unroll
            for (int r = 0; r < 4; ++r) {
                float pa = __expf(gl[0] + yv[0][r] - Gcur[r])
                         + __expf(gl[1] + yv[1][r] - Gcur[r]);
                pa += __shfl_xor(pa, 1, 16);
                pa += __shfl_xor(pa, 2, 16);
                pa += __shfl_xor(pa, 4, 16);
                pa += __shfl_xor(pa, 8, 16);
                if (li == 0) {
                    atomicAdd(&Psum[b0 + r], pa);
                    if (p == 0) Rbuf[b0 + r] = Gcur[r];
                }
            }
        }
    }
}

__global__ void k_final(const float* __restrict__ Psum, const float* __restrict__ Rbuf,
                        float* __restrict__ out) {
    int b = threadIdx.x;
    if (b < 32) out[b] = Rbuf[b] + __logf(Psum[b]);
}

extern "C" void kernel_launch(void* const* d_in, const int* in_sizes, int n_in,
                              void* d_out, int out_size, void* d_ws, size_t ws_size,
                              hipStream_t stream) {
    const int*   x     = (const int*)d_in[0];
    const float* alpha = (const float*)d_in[1];
    const float* beta  = (const float*)d_in[2];
    const float* gamma = (const float*)d_in[3];

    char* ws = (char*)d_ws;
    __bf16*  Abf  = (__bf16*)(ws + OFF_ABF);
    __bf16*  Ybuf = (__bf16*)(ws + OFF_YBUF);
    float*   Lbuf = (float*)(ws + OFF_LBUF);
    float*   Psum = (float*)(ws + OFF_PSUM);
    float*   Rbuf = (float*)(ws + OFF_RBUF);
    unsigned* cnt  = (unsigned*)(ws + OFF_CNT);
    unsigned* flag = (unsigned*)(ws + OFF_FLAG);

    // zero Psum / counter / flag (Rbuf overwritten anyway)
    hipMemsetAsync(ws + OFF_PSUM, 0, WS_NEED - OFF_PSUM, stream);

    hipLaunchKernelGGL(k_expA, dim3((Hdim * Hdim) / (256 * 4)), dim3(256), 0, stream, alpha, Abf);

    hipFuncSetAttribute((const void*)k_hmm, hipFuncAttributeMaxDynamicSharedMemorySize, SMEM_BYTES);
    hipLaunchKernelGGL(k_hmm, dim3(NWG), dim3(256), SMEM_BYTES, stream,
                       x, beta, gamma, Abf, Ybuf, Lbuf, Psum, Rbuf, cnt, flag);

    hipLaunchKernelGGL(k_final, dim3(1), dim3(64), 0, stream, Psum, Rbuf, (float*)d_out);
}